// Round 8
// baseline (441.850 us; speedup 1.0000x reference)
//
#include <hip/hip_runtime.h>
#include <hip/hip_bf16.h>
#include <stdint.h>

// Problem constants
#define M_DIM 8192   // B*S = 4*2048
#define N_C   4096   // contraction dim (N in reference)
#define K_OUT 4096   // output features (K in reference)
#define NGRP  32
#define NT    (N_C / 32)   // 128 K-tiles of 32

typedef __attribute__((ext_vector_type(8))) short bf16x8;
typedef __attribute__((ext_vector_type(4))) float f32x4;

// fp32 -> bf16, round-to-nearest-even (inputs are finite)
__device__ __forceinline__ unsigned short f2b(float f) {
  unsigned u = __float_as_uint(f);
  return (unsigned short)((u + 0x7fffu + ((u >> 16) & 1u)) >> 16);
}

__device__ __forceinline__ void gload_lds16(const void* g, void* l) {
  __builtin_amdgcn_global_load_lds(
      (const __attribute__((address_space(1))) void*)g,
      (__attribute__((address_space(3))) void*)l,
      16, 0, 0);
}

// ---- x fp32 -> bf16 ----
__global__ void convert_x_kernel(const float* __restrict__ x,
                                 unsigned short* __restrict__ xb) {
  const int total = (M_DIM * N_C) / 8;
  const int stride = gridDim.x * blockDim.x;
  for (int i = blockIdx.x * blockDim.x + threadIdx.x; i < total; i += stride) {
    const float4* p = (const float4*)(x + (size_t)i * 8);
    float4 a = p[0];
    float4 b = p[1];
    union { unsigned short u[8]; uint4 v; } o;
    o.u[0] = f2b(a.x); o.u[1] = f2b(a.y); o.u[2] = f2b(a.z); o.u[3] = f2b(a.w);
    o.u[4] = f2b(b.x); o.u[5] = f2b(b.y); o.u[6] = f2b(b.z); o.u[7] = f2b(b.w);
    *(uint4*)(xb + (size_t)i * 8) = o.v;
  }
}

// ---- W dequant -> bf16 [K_OUT][N_C] ----
__global__ void dequant_w_kernel(const int* __restrict__ Wq,
                                 const float* __restrict__ scales,
                                 const float* __restrict__ zeros,
                                 const float* __restrict__ mu1,
                                 const float* __restrict__ mu2,
                                 unsigned short* __restrict__ wb) {
  const int total = (K_OUT * N_C) / 8;
  const int stride = gridDim.x * blockDim.x;
  for (int i = blockIdx.x * blockDim.x + threadIdx.x; i < total; i += stride) {
    const int k  = i >> 9;
    const int nc = (i & 511) << 3;
    const int g  = nc >> 7;
    const float s = scales[k * NGRP + g];
    const float z = zeros[k * NGRP + g];
    const float f  = s * mu2[k];
    const float zf = z * f;
    const int4* q4 = (const int4*)(Wq + (size_t)k * N_C + nc);
    int4 q0 = q4[0], q1 = q4[1];
    const float4* m4 = (const float4*)(mu1 + nc);
    float4 m0 = m4[0], m1 = m4[1];
    union { unsigned short u[8]; uint4 v; } o;
    o.u[0] = f2b(((float)q0.x * f - zf) * m0.x);
    o.u[1] = f2b(((float)q0.y * f - zf) * m0.y);
    o.u[2] = f2b(((float)q0.z * f - zf) * m0.z);
    o.u[3] = f2b(((float)q0.w * f - zf) * m0.w);
    o.u[4] = f2b(((float)q1.x * f - zf) * m1.x);
    o.u[5] = f2b(((float)q1.y * f - zf) * m1.y);
    o.u[6] = f2b(((float)q1.z * f - zf) * m1.z);
    o.u[7] = f2b(((float)q1.w * f - zf) * m1.w);
    *(uint4*)(wb + (size_t)i * 8) = o.v;
  }
}

// ---- Hybrid bf16 GEMM (flatmm-style): out[m][n] = sum_k Xb[m][k]*Wb[n][k]+b
// 256x256 tile, BK=32, 8 waves (2Mx4N, per-wave 128x64), MFMA 16x16x32.
// A: LDS, 4 bufs x 16KB (R3's proven 0-conflict swizzle), staged by
//    global_load_lds, A-frags read ONE TILE AHEAD into reg ping-pong.
// B: NO LDS - 4 frags/wave loaded direct from global (L1/L2-resident tile)
//    into reg ping-pong, one tile ahead.
// Body t: {vmcnt(6)+barrier; ds_read A(t+1)->NXT; load B(t+1)->NXT;
//          stageA(t+3); 32 MFMA on CUR regs (register-only)} -> DS+VMEM
// service of t+1 overlaps MFMA(t).
// vmcnt ledger (body tau issues: loadB(tau+1)[4] then stageA(tau+3)[2]):
//   top of body t outstanding (oldest->newest):
//   stageA(t+1)[2], loadB(t)[4], stageA(t+2)[2]  (loadB(t-1) proven done by
//   body t-1's auto-wait before MFMA(t-1)). vmcnt(6) proves stageA(t+1);
//   barrier makes buf[(t+1)&3] valid CU-wide before the NXT ds_reads.
//   B(t) regs are proven by the compiler's auto vmcnt before first MFMA use.
// Buffer safety: stageA(t+3) (issued after barrier(t)) overwrites
//   buf[(t-1)&3]; every wave's A(t-1) ds_reads were lgkm-drained before its
//   MFMA(t-1) (program order, before barrier(t)) -> no race.
__global__ __launch_bounds__(512, 2) void gemm_bf16_kernel(
    const unsigned short* __restrict__ Xb,   // [M_DIM][N_C] bf16
    const unsigned short* __restrict__ Wb,   // [K_OUT][N_C] bf16
    const float* __restrict__ bias,          // [K_OUT]
    float* __restrict__ out) {               // [M_DIM][K_OUT]
  __shared__ unsigned short smem[32768];     // 64 KiB: 4 bufs x 16 KiB (A only)

  // XCD map: XCD x (bid&7) covers n-cols {2x, 2x+1} -> B-tile (2MB) stays in
  // that XCD's L2; bijective over 512 blocks (8 x 2 x 32).
  const int bid = blockIdx.x;
  const int x8  = bid & 7;
  const int ii  = bid >> 3;            // 0..63
  const int n0 = (2 * x8 + (ii >> 5)) * 256;
  const int m0 = (ii & 31) * 256;

  const int tid = threadIdx.x;
  const int w   = tid >> 6;
  const int l   = tid & 63;
  const int wr  = w >> 2;     // 0..1 -> 128 rows
  const int wc  = w & 3;      // 0..3 -> 64 cols

  const char* Xc = (const char*)Xb;
  const char* Wc = (const char*)Wb;
  char* ldsc = (char*)smem;

  // ---- A staging (R3 pattern, A-only 16KB/tile): linear LDS dst,
  //      inverse-swizzled global src ----
  const char* srcA[2];
  int dstOff[2];
#pragma unroll
  for (int e = 0; e < 2; ++e) {
    const int P  = (e * 8 + w) * 1024 + l * 16;   // byte in 16KB tile
    const int r  = P >> 6;                         // 64B per row
    const int sl = ((P >> 4) & 3) ^ ((r >> 1) & 3);
    srcA[e] = Xc + (size_t)(m0 + r) * 8192 + sl * 16;
    dstOff[e] = (e * 8 + w) * 1024;
  }

  // ---- A ds_read base (R3's proven 0-conflict geometry) ----
  // frag i: row r = wr*128 + i*16 + (l&15); sl = (l>>4) ^ ((r>>1)&3).
  // (r>>1)&3 is i-invariant (i*16 -> +8 in r>>1, = 0 mod 4) -> single base.
  const int r0   = wr * 128 + (l & 15);
  const int sl0  = (l >> 4) ^ ((r0 >> 1) & 3);
  const int offa0 = r0 * 64 + sl0 * 16;            // + i*1024

  // ---- B direct-load base: frag j rows n0 + wc*64 + j*16 + (l&15),
  //      k-slice (l>>4)*16B within the tile's 64B ----
  const char* srcB = Wc + (size_t)(n0 + wc * 64 + (l & 15)) * 8192 + (l >> 4) * 16;

  f32x4 acc[8][4] = {};
  bf16x8 Ar[2][8];
  bf16x8 Br[2][4];

#define STAGEA(tt) { char* nb = ldsc + ((tt) & 3) * 16384;                   \
    const size_t ko = (size_t)(tt) * 64;                                     \
    gload_lds16(srcA[0] + ko, nb + dstOff[0]);                               \
    gload_lds16(srcA[1] + ko, nb + dstOff[1]); }

#define BODY(VMSTR, tt, CUR, NXT, DOREAD, DOLOADB, DOSTAGE)                  \
  { asm volatile("s_waitcnt vmcnt(" VMSTR ")\n\ts_barrier" ::: "memory");    \
    if (DOREAD) { const char* bp = ldsc + (((tt) + 1) & 3) * 16384 + offa0;  \
      _Pragma("unroll") for (int i = 0; i < 8; ++i)                          \
        Ar[NXT][i] = *(const bf16x8*)(bp + i * 1024); }                      \
    if (DOLOADB) { const char* q = srcB + (size_t)((tt) + 1) * 64;           \
      _Pragma("unroll") for (int j = 0; j < 4; ++j)                          \
        Br[NXT][j] = *(const bf16x8*)(q + (size_t)j * 131072); }             \
    if (DOSTAGE) STAGEA((tt) + 3)                                            \
    __builtin_amdgcn_s_setprio(1);                                           \
    _Pragma("unroll") for (int i = 0; i < 8; ++i)                            \
      _Pragma("unroll") for (int j = 0; j < 4; ++j)                          \
        acc[i][j] = __builtin_amdgcn_mfma_f32_16x16x32_bf16(Ar[CUR][i],      \
            Br[CUR][j], acc[i][j], 0, 0, 0);                                 \
    __builtin_amdgcn_s_setprio(0); }

  // Prologue: stage A(0,1,2) [6 loads], load B(0) [4 loads];
  // vmcnt(8) proves stageA(0) (8 newer: stageA(1,2)=4 + loadB(0)=4).
  STAGEA(0)
  STAGEA(1)
  STAGEA(2)
#pragma unroll
  for (int j = 0; j < 4; ++j)
    Br[0][j] = *(const bf16x8*)(srcB + (size_t)j * 131072);
  asm volatile("s_waitcnt vmcnt(8)\n\ts_barrier" ::: "memory");
#pragma unroll
  for (int i = 0; i < 8; ++i)
    Ar[0][i] = *(const bf16x8*)(ldsc + offa0 + i * 1024);

  // Main: bodies t=0..123 uniform (vmcnt(6), read/loadB t+1, stage t+3).
#pragma unroll 1
  for (int tp = 0; tp < NT / 2 - 2; ++tp) {
    BODY("6", 2 * tp,     0, 1, 1, 1, 1)
    BODY("6", 2 * tp + 1, 1, 0, 1, 1, 1)
  }
  // Tail: t=124 stages A(127); 125/126 no stage; 127 MFMA-only.
  BODY("6", NT - 4, 0, 1, 1, 1, 1)
  BODY("6", NT - 3, 1, 0, 1, 1, 0)
  BODY("4", NT - 2, 0, 1, 1, 1, 0)   // vmcnt(4) proves stageA(127)
  BODY("0", NT - 1, 1, 0, 0, 0, 0)

#undef BODY
#undef STAGEA

  // Epilogue: C/D layout col=lane&15, row=(lane>>4)*4+reg (verified R1/R2).
#pragma unroll
  for (int j = 0; j < 4; ++j) {
    const int col = n0 + wc * 64 + j * 16 + (l & 15);
    const float bv = bias[col];
#pragma unroll
    for (int i = 0; i < 8; ++i) {
      const int row = m0 + wr * 128 + i * 16 + (l >> 4) * 4;
#pragma unroll
      for (int rr = 0; rr < 4; ++rr)
        out[(size_t)(row + rr) * K_OUT + col] = acc[i][j][rr] + bv;
    }
  }
}

extern "C" void kernel_launch(void* const* d_in, const int* in_sizes, int n_in,
                              void* d_out, int out_size, void* d_ws, size_t ws_size,
                              hipStream_t stream) {
  const float* x      = (const float*)d_in[0];
  const int*   Wq     = (const int*)d_in[1];
  const float* scales = (const float*)d_in[2];
  const float* zeros  = (const float*)d_in[3];
  const float* mu1    = (const float*)d_in[4];
  const float* mu2    = (const float*)d_in[5];
  const float* bias   = (const float*)d_in[6];
  float* out = (float*)d_out;

  unsigned short* xb = (unsigned short*)d_ws;
  unsigned short* wb = xb + (size_t)M_DIM * N_C;

  convert_x_kernel<<<2048, 256, 0, stream>>>(x, xb);
  dequant_w_kernel<<<2048, 256, 0, stream>>>(Wq, scales, zeros, mu1, mu2, wb);

  dim3 grid((M_DIM / 256) * (K_OUT / 256));   // 512 blocks
  gemm_bf16_kernel<<<grid, 512, 0, stream>>>(xb, wb, bias, out);
}

// Round 9
// 305.796 us; speedup vs baseline: 1.4449x; 1.4449x over previous
//
#include <hip/hip_runtime.h>
#include <hip/hip_bf16.h>
#include <stdint.h>

// Problem constants
#define M_DIM 8192   // B*S = 4*2048
#define N_C   4096   // contraction dim (N in reference)
#define K_OUT 4096   // output features (K in reference)
#define NGRP  32
#define NT    (N_C / 32)   // 128 K-tiles of 32

typedef __attribute__((ext_vector_type(8))) short bf16x8;
typedef __attribute__((ext_vector_type(4))) float f32x4;

// fp32 -> bf16, round-to-nearest-even (inputs are finite)
__device__ __forceinline__ unsigned short f2b(float f) {
  unsigned u = __float_as_uint(f);
  return (unsigned short)((u + 0x7fffu + ((u >> 16) & 1u)) >> 16);
}

__device__ __forceinline__ void gload_lds16(const void* g, void* l) {
  __builtin_amdgcn_global_load_lds(
      (const __attribute__((address_space(1))) void*)g,
      (__attribute__((address_space(3))) void*)l,
      16, 0, 0);
}

// ---- x fp32 -> bf16 ----
__global__ void convert_x_kernel(const float* __restrict__ x,
                                 unsigned short* __restrict__ xb) {
  const int total = (M_DIM * N_C) / 8;
  const int stride = gridDim.x * blockDim.x;
  for (int i = blockIdx.x * blockDim.x + threadIdx.x; i < total; i += stride) {
    const float4* p = (const float4*)(x + (size_t)i * 8);
    float4 a = p[0];
    float4 b = p[1];
    union { unsigned short u[8]; uint4 v; } o;
    o.u[0] = f2b(a.x); o.u[1] = f2b(a.y); o.u[2] = f2b(a.z); o.u[3] = f2b(a.w);
    o.u[4] = f2b(b.x); o.u[5] = f2b(b.y); o.u[6] = f2b(b.z); o.u[7] = f2b(b.w);
    *(uint4*)(xb + (size_t)i * 8) = o.v;
  }
}

// ---- W dequant -> bf16 [K_OUT][N_C] ----
__global__ void dequant_w_kernel(const int* __restrict__ Wq,
                                 const float* __restrict__ scales,
                                 const float* __restrict__ zeros,
                                 const float* __restrict__ mu1,
                                 const float* __restrict__ mu2,
                                 unsigned short* __restrict__ wb) {
  const int total = (K_OUT * N_C) / 8;
  const int stride = gridDim.x * blockDim.x;
  for (int i = blockIdx.x * blockDim.x + threadIdx.x; i < total; i += stride) {
    const int k  = i >> 9;
    const int nc = (i & 511) << 3;
    const int g  = nc >> 7;
    const float s = scales[k * NGRP + g];
    const float z = zeros[k * NGRP + g];
    const float f  = s * mu2[k];
    const float zf = z * f;
    const int4* q4 = (const int4*)(Wq + (size_t)k * N_C + nc);
    int4 q0 = q4[0], q1 = q4[1];
    const float4* m4 = (const float4*)(mu1 + nc);
    float4 m0 = m4[0], m1 = m4[1];
    union { unsigned short u[8]; uint4 v; } o;
    o.u[0] = f2b(((float)q0.x * f - zf) * m0.x);
    o.u[1] = f2b(((float)q0.y * f - zf) * m0.y);
    o.u[2] = f2b(((float)q0.z * f - zf) * m0.z);
    o.u[3] = f2b(((float)q0.w * f - zf) * m0.w);
    o.u[4] = f2b(((float)q1.x * f - zf) * m1.x);
    o.u[5] = f2b(((float)q1.y * f - zf) * m1.y);
    o.u[6] = f2b(((float)q1.z * f - zf) * m1.z);
    o.u[7] = f2b(((float)q1.w * f - zf) * m1.w);
    *(uint4*)(wb + (size_t)i * 8) = o.v;
  }
}

// ---- Register-pipelined bf16 GEMM: out[m][n] = sum_k Xb[m][k]*Wb[n][k]+bias
// 256x256 tile, BK=32, 8 waves (2Mx4N, per-wave 128x64), MFMA 16x16x32.
// LDS: 4 bufs x 32KB (A 16KB + B 16KB), R2/R3's verified 0-conflict swizzle,
// staged by global_load_lds (coalesced 16B/lane - fixes R8's over-fetch).
// Register ping-pong (R8's structure): frags(t+1) ds_read into NXT set while
// MFMA(t) runs on CUR set (register-only; compiler emits counted lgkmcnt(12)
// since LDS completes in order) -> LDS service overlaps MFMA stream.
// vmcnt ledger (stage = 4 gload_lds; body tau issues stage(tau+3)):
//   top of body t outstanding: stage(t+1)[4] + stage(t+2)[4] = 8.
//   vmcnt(4) proves stage(t+1) - exactly the buffer frags(t+1) read.
//   Barrier makes it CU-wide.
// Buffer safety: stage(t+3) (after barrier(t)) overwrites buf[(t-1)&3];
//   frags(t-1) reads (body t-2) were lgkm-drained before MFMA(t-1) (body
//   t-1, program order) - before every wave passed barrier(t). No race.
__global__ __launch_bounds__(512, 2) void gemm_bf16_kernel(
    const unsigned short* __restrict__ Xb,   // [M_DIM][N_C] bf16
    const unsigned short* __restrict__ Wb,   // [K_OUT][N_C] bf16
    const float* __restrict__ bias,          // [K_OUT]
    float* __restrict__ out) {               // [M_DIM][K_OUT]
  __shared__ unsigned short smem[65536];     // 128 KiB: 4 bufs x 32 KiB

  // XCD-aware bijective swizzle: 512 blocks, 8 XCDs, 64 per XCD
  const int bid = blockIdx.x;
  const int swz = (bid & 7) * 64 + (bid >> 3);
  const int n0 = (swz & 15) * 256;
  const int m0 = (swz >> 4) * 256;

  const int tid = threadIdx.x;
  const int w   = tid >> 6;
  const int l   = tid & 63;
  const int wr  = w >> 2;     // 0..1 -> 128 rows
  const int wc  = w & 3;      // 0..3 -> 64 cols

  const char* Xc = (const char*)Xb;
  const char* Wc = (const char*)Wb;
  char* ldsc = (char*)smem;

  // ---- staging (R3-identical): linear LDS dst, inverse-swizzled src ----
  const char* srcA[2];
  const char* srcB[2];
  int dstOff[2];
#pragma unroll
  for (int e = 0; e < 2; ++e) {
    const int P  = (e * 8 + w) * 1024 + l * 16;
    const int r  = P >> 6;
    const int sl = ((P >> 4) & 3) ^ ((r >> 1) & 3);
    srcA[e] = Xc + (size_t)(m0 + r) * 8192 + sl * 16;
    srcB[e] = Wc + (size_t)(n0 + r) * 8192 + sl * 16;
    dstOff[e] = (e * 8 + w) * 1024;
  }

  // ---- swizzled ds_read bases (R3's proven 0-conflict geometry) ----
  // A frag i: row r = wr*128 + i*16 + (l&15); sl = (l>>4)^((r>>1)&3);
  // (r>>1)&3 is i-invariant -> single base + i*1024. Same for B with wc*64.
  const int rA0  = wr * 128 + (l & 15);
  const int offa0 = rA0 * 64 + ((l >> 4) ^ ((rA0 >> 1) & 3)) * 16;
  const int rB0  = wc * 64 + (l & 15);
  const int offb0 = 16384 + rB0 * 64 + ((l >> 4) ^ ((rB0 >> 1) & 3)) * 16;

  f32x4 acc[8][4] = {};
  bf16x8 Ar[2][8];
  bf16x8 Br[2][4];

#define STAGE(tt) { char* nb = ldsc + ((tt) & 3) * 32768;                    \
    const size_t ko = (size_t)(tt) * 64;                                     \
    gload_lds16(srcA[0] + ko, nb + dstOff[0]);                               \
    gload_lds16(srcA[1] + ko, nb + dstOff[1]);                               \
    gload_lds16(srcB[0] + ko, nb + 16384 + dstOff[0]);                       \
    gload_lds16(srcB[1] + ko, nb + 16384 + dstOff[1]); }

#define BODY(VMSTR, tt, CUR, NXT, DOREAD, DOSTAGE)                           \
  { asm volatile("s_waitcnt vmcnt(" VMSTR ")\n\ts_barrier" ::: "memory");    \
    if (DOREAD) { const char* bp = ldsc + (((tt) + 1) & 3) * 32768;          \
      Br[NXT][0] = *(const bf16x8*)(bp + offb0);                             \
      _Pragma("unroll") for (int i = 0; i < 8; ++i)                          \
        Ar[NXT][i] = *(const bf16x8*)(bp + offa0 + i * 1024);                \
      _Pragma("unroll") for (int j = 1; j < 4; ++j)                          \
        Br[NXT][j] = *(const bf16x8*)(bp + offb0 + j * 1024); }              \
    if (DOSTAGE) STAGE((tt) + 3)                                             \
    __builtin_amdgcn_s_setprio(1);                                           \
    _Pragma("unroll") for (int i = 0; i < 8; ++i)                            \
      _Pragma("unroll") for (int j = 0; j < 4; ++j)                          \
        acc[i][j] = __builtin_amdgcn_mfma_f32_16x16x32_bf16(Ar[CUR][i],      \
            Br[CUR][j], acc[i][j], 0, 0, 0);                                 \
    __builtin_amdgcn_s_setprio(0); }

  // Prologue: stage 0,1,2 (12 loads); vmcnt(8) proves stage(0); read frags(0).
  STAGE(0)
  STAGE(1)
  STAGE(2)
  asm volatile("s_waitcnt vmcnt(8)\n\ts_barrier" ::: "memory");
#pragma unroll
  for (int i = 0; i < 8; ++i)
    Ar[0][i] = *(const bf16x8*)(ldsc + offa0 + i * 1024);
#pragma unroll
  for (int j = 0; j < 4; ++j)
    Br[0][j] = *(const bf16x8*)(ldsc + offb0 + j * 1024);

  // Main: bodies t=0..123 uniform (vmcnt(4), read t+1, stage t+3 <= 126).
#pragma unroll 1
  for (int tp = 0; tp < NT / 2 - 2; ++tp) {
    BODY("4", 2 * tp,     0, 1, 1, 1)
    BODY("4", 2 * tp + 1, 1, 0, 1, 1)
  }
  // Tail: body 124 stages 127 (last); 125,126 no stage; 127 MFMA-only.
  BODY("4", NT - 4, 0, 1, 1, 1)
  BODY("4", NT - 3, 1, 0, 1, 0)
  BODY("0", NT - 2, 0, 1, 1, 0)
  // Final body: MFMA on set1 (frags(127)); no reads/stage/barrier needed.
  __builtin_amdgcn_s_setprio(1);
#pragma unroll
  for (int i = 0; i < 8; ++i)
#pragma unroll
    for (int j = 0; j < 4; ++j)
      acc[i][j] = __builtin_amdgcn_mfma_f32_16x16x32_bf16(Ar[1][i], Br[1][j],
                                                          acc[i][j], 0, 0, 0);
  __builtin_amdgcn_s_setprio(0);

#undef BODY
#undef STAGE

  // Epilogue: C/D layout col=lane&15, row=(lane>>4)*4+reg (verified R1/R2).
#pragma unroll
  for (int j = 0; j < 4; ++j) {
    const int col = n0 + wc * 64 + j * 16 + (l & 15);
    const float bv = bias[col];
#pragma unroll
    for (int i = 0; i < 8; ++i) {
      const int row = m0 + wr * 128 + i * 16 + (l >> 4) * 4;
#pragma unroll
      for (int rr = 0; rr < 4; ++rr)
        out[(size_t)(row + rr) * K_OUT + col] = acc[i][j][rr] + bv;
    }
  }
}

extern "C" void kernel_launch(void* const* d_in, const int* in_sizes, int n_in,
                              void* d_out, int out_size, void* d_ws, size_t ws_size,
                              hipStream_t stream) {
  const float* x      = (const float*)d_in[0];
  const int*   Wq     = (const int*)d_in[1];
  const float* scales = (const float*)d_in[2];
  const float* zeros  = (const float*)d_in[3];
  const float* mu1    = (const float*)d_in[4];
  const float* mu2    = (const float*)d_in[5];
  const float* bias   = (const float*)d_in[6];
  float* out = (float*)d_out;

  unsigned short* xb = (unsigned short*)d_ws;
  unsigned short* wb = xb + (size_t)M_DIM * N_C;

  convert_x_kernel<<<2048, 256, 0, stream>>>(x, xb);
  dequant_w_kernel<<<2048, 256, 0, stream>>>(Wq, scales, zeros, mu1, mu2, wb);

  dim3 grid((M_DIM / 256) * (K_OUT / 256));   // 512 blocks
  gemm_bf16_kernel<<<grid, 512, 0, stream>>>(xb, wb, bias, out);
}